// Round 3
// baseline (77.470 us; speedup 1.0000x reference)
//
#include <hip/hip_runtime.h>

#define N_GENERA 4096
#define N_RANKS 6
#define N_GROUPS 256
#define NCH 7                          // 6 ranks + identity channel
#define SEG_SZ (N_RANKS * N_GROUPS)    // 1536
#define EXT_SZ (SEG_SZ + N_GENERA)     // legacy: 5632 float2 = 45 KB
#define NF (N_GENERA * NCH)            // 28672 output floats per b
#define NF4 (NF / 4)                   // 7168 float4 per b

// gather geometry
#define GT 448                         // gather threads (7 waves)
#define JCH 1024                       // j's per chunk
#define NCHUNK 4
#define GRP_PER_BLK 1792               // JCH*NCH/4 float4-groups per block
#define EXT4_SZ (SEG_SZ + JCH)         // 2560 f32x4 = 40 KB

typedef float f32x4 __attribute__((ext_vector_type(4)));

// ws layout:
//   idx   [6][4096] int   @ 0        (96 KB)
//   offs  [6][260]  int   @ 98304
//   sidxN [NF]      short @ 104704   (chunk-local ext4 index)
//   sidxO [NF]      short @ 162048   (legacy ext index)
//   perm  [1536]    int   @ 219392   (length-sorted (r,g) order)
//   seg   [B/4][1536] f32x4 @ 225536 (6 MB, quad-interleaved seg sums)
#define WS_IDX_OFF   0
#define WS_OFFS_OFF  98304
#define WS_SIDXN_OFF 104704
#define WS_SIDXO_OFF 162048
#define WS_PERM_OFF  219392
#define WS_SEG_OFF   225536

__device__ __forceinline__ int imin(int a, int b) { return a < b ? a : b; }

// ---------- Kernel 0: prep ----------
// blocks 0..5: per-rank CSR; 6..117: sidxN; 118..229: sidxO; 230: perm
__global__ __launch_bounds__(256) void prep_kernel(
    const int* __restrict__ labels,
    int* __restrict__ idx,      // [R][N_GENERA]
    int* __restrict__ offs,     // [R][260]
    short* __restrict__ sidxN,
    short* __restrict__ sidxO,
    int* __restrict__ perm)
{
    const int t = threadIdx.x;

    if (blockIdx.x < N_RANKS) {
        const int r = blockIdx.x;
        const int* __restrict__ lab = labels + r * N_GENERA;

        __shared__ int cnt[N_GROUPS];
        __shared__ int scan[N_GROUPS];
        __shared__ int cur[N_GROUPS];

        cnt[t] = 0;
        __syncthreads();
        for (int i = t; i < N_GENERA; i += 256)
            atomicAdd(&cnt[lab[i]], 1);
        __syncthreads();

        int v = cnt[t];
        scan[t] = v;
        __syncthreads();
        #pragma unroll
        for (int s = 1; s < 256; s <<= 1) {
            int add = (t >= s) ? scan[t - s] : 0;
            __syncthreads();
            scan[t] += add;
            __syncthreads();
        }
        int start = scan[t] - v;          // exclusive prefix
        cur[t] = start;
        offs[r * 260 + t] = start;
        if (t == 0) offs[r * 260 + 256] = N_GENERA;
        __syncthreads();
        for (int i = t; i < N_GENERA; i += 256) {
            int p = atomicAdd(&cur[lab[i]], 1);
            idx[r * N_GENERA + p] = i;
        }
    } else if (blockIdx.x < N_RANKS + 112) {
        // sidxN: chunk-local ext4 index (seg slot or 1536 + (j&1023))
        const int f = (blockIdx.x - N_RANKS) * 256 + t;   // < NF
        const int j = f / NCH;
        const int ch = f - j * NCH;
        int v;
        if (ch < N_RANKS)
            v = ch * N_GROUPS + labels[ch * N_GENERA + j];
        else
            v = SEG_SZ + (j & (JCH - 1));
        sidxN[f] = (short)v;
    } else if (blockIdx.x < N_RANKS + 224) {
        // sidxO: legacy ext index (seg slot or 1536 + j)
        const int f = (blockIdx.x - N_RANKS - 112) * 256 + t;
        const int j = f / NCH;
        const int ch = f - j * NCH;
        int v;
        if (ch < N_RANKS)
            v = ch * N_GROUPS + labels[ch * N_GENERA + j];
        else
            v = SEG_SZ + j;
        sidxO[f] = (short)v;
    } else {
        // perm: count-sort the 1536 (r,g) items by descending count, so a
        // wave's 64 lanes get near-equal CSR list lengths (kills divergence).
        __shared__ int cnt[SEG_SZ];
        __shared__ int hist[64];
        __shared__ int base[64];
        __shared__ int cur[64];
        for (int i = t; i < SEG_SZ; i += 256) cnt[i] = 0;
        if (t < 64) { hist[t] = 0; cur[t] = 0; }
        __syncthreads();
        for (int r = 0; r < N_RANKS; ++r)
            for (int i = t; i < N_GENERA; i += 256)
                atomicAdd(&cnt[r * N_GROUPS + labels[r * N_GENERA + i]], 1);
        __syncthreads();
        for (int p = t; p < SEG_SZ; p += 256)
            atomicAdd(&hist[imin(cnt[p], 63)], 1);
        __syncthreads();
        if (t < 64) {
            int bsum = 0;
            for (int c = t + 1; c < 64; ++c) bsum += hist[c];
            base[t] = bsum;               // descending-count exclusive base
        }
        __syncthreads();
        for (int p = t; p < SEG_SZ; p += 256) {
            int c = imin(cnt[p], 63);
            int slot = base[c] + atomicAdd(&cur[c], 1);
            perm[slot] = p;
        }
    }
}

// ---------- Kernel 1: seg sums, 4 batch rows per block ----------
// LDS F4[4096] = {F[b0..b0+3][i]} (64 KB). Balanced CSR items via perm;
// one ds_read_b128 serves 4 batch rows. Writes quad-interleaved seg.
__global__ __launch_bounds__(512) void seg_kernel(
    const float* __restrict__ F,
    const int* __restrict__ idx,
    const int* __restrict__ offs,
    const int* __restrict__ perm,
    float* __restrict__ seg)          // f32x4 [B/4][1536]
{
    __shared__ f32x4 F4[N_GENERA];
    const int q = blockIdx.x;
    const int b0 = q * 4;
    const int t = threadIdx.x;

    const f32x4* Fv0 = reinterpret_cast<const f32x4*>(F + (size_t)b0 * N_GENERA);
    const f32x4* Fv1 = reinterpret_cast<const f32x4*>(F + (size_t)(b0 + 1) * N_GENERA);
    const f32x4* Fv2 = reinterpret_cast<const f32x4*>(F + (size_t)(b0 + 2) * N_GENERA);
    const f32x4* Fv3 = reinterpret_cast<const f32x4*>(F + (size_t)(b0 + 3) * N_GENERA);
    #pragma unroll
    for (int w = 0; w < 2; ++w) {
        const int T = t + w * 512;            // < 1024 f4-groups
        const f32x4 a0 = __builtin_nontemporal_load(Fv0 + T);
        const f32x4 a1 = __builtin_nontemporal_load(Fv1 + T);
        const f32x4 a2 = __builtin_nontemporal_load(Fv2 + T);
        const f32x4 a3 = __builtin_nontemporal_load(Fv3 + T);
        #pragma unroll
        for (int k = 0; k < 4; ++k) {
            f32x4 v;
            v[0] = a0[k]; v[1] = a1[k]; v[2] = a2[k]; v[3] = a3[k];
            F4[4 * T + k] = v;
        }
    }
    __syncthreads();

    f32x4* __restrict__ segq = reinterpret_cast<f32x4*>(seg) + (size_t)q * SEG_SZ;
    #pragma unroll
    for (int w = 0; w < 3; ++w) {
        const int p = perm[w * 512 + t];
        const int r = p >> 8;
        const int g = p & 255;
        const int e = offs[r * 260 + g + 1];
        int k = offs[r * 260 + g];
        const int* __restrict__ ip = idx + r * N_GENERA;
        f32x4 s = {0.f, 0.f, 0.f, 0.f};
        for (; k + 4 <= e; k += 4) {
            const int i0 = ip[k], i1 = ip[k + 1], i2 = ip[k + 2], i3 = ip[k + 3];
            f32x4 x0 = F4[i0], x1 = F4[i1], x2 = F4[i2], x3 = F4[i3];
            s += (x0 + x1) + (x2 + x3);
        }
        for (; k < e; ++k) s += F4[ip[k]];
        segq[p] = s;
    }
}

// ---------- Kernel 2: gather + store, 4 b x 1024-j chunk per block ----------
// LDS ext4 = { seg quads [1536] | F chunk quads [1024] } = 40 KB.
// Coalesced in, ds_read_b128 random gather (serves 4 b's), 4 coalesced
// nontemporal float4 store streams. 4 blocks/CU.
__global__ __launch_bounds__(GT) void gather_kernel(
    const float* __restrict__ F,
    const float* __restrict__ seg,    // f32x4 [B/4][1536]
    const short* __restrict__ sidx,   // chunk-local ext4 index
    float* __restrict__ out)
{
    __shared__ f32x4 ext4[EXT4_SZ];
    const int blk = blockIdx.x;
    const int q = blk >> 2;           // batch quad
    const int c = blk & 3;            // j-chunk
    const int t = threadIdx.x;
    const int b0 = q * 4;

    // seg quads -> LDS (coalesced b128)
    const f32x4* sg = reinterpret_cast<const f32x4*>(seg) + (size_t)q * SEG_SZ;
    for (int i = t; i < SEG_SZ; i += GT) ext4[i] = sg[i];

    // F chunk -> LDS quad-interleaved
    {
        const int jbase = c * JCH;
        const f32x4* Fq0 = reinterpret_cast<const f32x4*>(F + (size_t)b0 * N_GENERA + jbase);
        const f32x4* Fq1 = reinterpret_cast<const f32x4*>(F + (size_t)(b0 + 1) * N_GENERA + jbase);
        const f32x4* Fq2 = reinterpret_cast<const f32x4*>(F + (size_t)(b0 + 2) * N_GENERA + jbase);
        const f32x4* Fq3 = reinterpret_cast<const f32x4*>(F + (size_t)(b0 + 3) * N_GENERA + jbase);
        if (t < JCH / 4) {
            const f32x4 a0 = __builtin_nontemporal_load(Fq0 + t);
            const f32x4 a1 = __builtin_nontemporal_load(Fq1 + t);
            const f32x4 a2 = __builtin_nontemporal_load(Fq2 + t);
            const f32x4 a3 = __builtin_nontemporal_load(Fq3 + t);
            #pragma unroll
            for (int k = 0; k < 4; ++k) {
                f32x4 v;
                v[0] = a0[k]; v[1] = a1[k]; v[2] = a2[k]; v[3] = a3[k];
                ext4[SEG_SZ + 4 * t + k] = v;
            }
        }
    }
    __syncthreads();

    f32x4* __restrict__ op0 = reinterpret_cast<f32x4*>(out) + (size_t)b0 * NF4 + c * GRP_PER_BLK;
    f32x4* __restrict__ op1 = op0 + NF4;
    f32x4* __restrict__ op2 = op1 + NF4;
    f32x4* __restrict__ op3 = op2 + NF4;
    const short* __restrict__ sx = sidx + (size_t)c * (JCH * NCH);
    #pragma unroll
    for (int g = 0; g < 4; ++g) {
        const int m = g * GT + t;     // < 1792
        short4 s4 = *reinterpret_cast<const short4*>(sx + 4 * m);
        f32x4 v0 = ext4[s4.x];
        f32x4 v1 = ext4[s4.y];
        f32x4 v2 = ext4[s4.z];
        f32x4 v3 = ext4[s4.w];
        f32x4 w0, w1, w2, w3;
        w0[0] = v0[0]; w0[1] = v1[0]; w0[2] = v2[0]; w0[3] = v3[0];
        w1[0] = v0[1]; w1[1] = v1[1]; w1[2] = v2[1]; w1[3] = v3[1];
        w2[0] = v0[2]; w2[1] = v1[2]; w2[2] = v2[2]; w2[3] = v3[2];
        w3[0] = v0[3]; w3[1] = v1[3]; w3[2] = v2[3]; w3[3] = v3[3];
        __builtin_nontemporal_store(w0, op0 + m);
        __builtin_nontemporal_store(w1, op1 + m);
        __builtin_nontemporal_store(w2, op2 + m);
        __builtin_nontemporal_store(w3, op3 + m);
    }
}

// ---------- Legacy fused kernel (fallback when ws too small) ----------
__global__ __launch_bounds__(512) void fused_kernel(
    const float* __restrict__ F,
    const int* __restrict__ idx,
    const int* __restrict__ offs,
    const short* __restrict__ sidx,
    float* __restrict__ out)
{
    __shared__ float2 ext2[EXT_SZ];
    const int b0 = blockIdx.x * 2;
    const int t = threadIdx.x;

    const float2 z2 = {0.f, 0.f};
    ext2[t] = z2; ext2[t + 512] = z2; ext2[t + 1024] = z2;

    const f32x4* Fv0 = reinterpret_cast<const f32x4*>(F + (size_t)b0 * N_GENERA);
    const f32x4* Fv1 = reinterpret_cast<const f32x4*>(F + (size_t)(b0 + 1) * N_GENERA);
    f32x4* Flv = reinterpret_cast<f32x4*>(ext2 + SEG_SZ);
    #pragma unroll
    for (int k = 0; k < 2; ++k) {
        const f32x4 a = __builtin_nontemporal_load(Fv0 + t + k * 512);
        const f32x4 c = __builtin_nontemporal_load(Fv1 + t + k * 512);
        f32x4 lo, hi;
        lo[0] = a[0]; lo[1] = c[0]; lo[2] = a[1]; lo[3] = c[1];
        hi[0] = a[2]; hi[1] = c[2]; hi[2] = a[3]; hi[3] = c[3];
        Flv[2 * (t + k * 512)]     = lo;
        Flv[2 * (t + k * 512) + 1] = hi;
    }
    __syncthreads();

    const float2* __restrict__ Fl2 = ext2 + SEG_SZ;
    #pragma unroll
    for (int w = 0; w < 3; ++w) {
        const int item = t + w * 512;
        const int r = item >> 8;
        const int g = item & 255;
        const int e = offs[r * 260 + g + 1];
        int k = offs[r * 260 + g];
        const int* __restrict__ ip = idx + r * N_GENERA;
        float sa = 0.f, sb = 0.f;
        for (; k + 4 <= e; k += 4) {
            int i0 = ip[k], i1 = ip[k + 1], i2 = ip[k + 2], i3 = ip[k + 3];
            float2 v0 = Fl2[i0], v1 = Fl2[i1], v2 = Fl2[i2], v3 = Fl2[i3];
            sa += (v0.x + v1.x) + (v2.x + v3.x);
            sb += (v0.y + v1.y) + (v2.y + v3.y);
        }
        for (; k < e; ++k) {
            float2 v = Fl2[ip[k]];
            sa += v.x; sb += v.y;
        }
        float2 sp; sp.x = sa; sp.y = sb;
        ext2[item] = sp;
    }
    __syncthreads();

    f32x4* __restrict__ op0 = reinterpret_cast<f32x4*>(out) + (size_t)b0 * NF4;
    f32x4* __restrict__ op1 = op0 + NF4;
    #pragma unroll
    for (int kk = 0; kk < 14; ++kk) {
        const int qq = kk * 512 + t;
        short4 s4 = *reinterpret_cast<const short4*>(sidx + qq * 4);
        float2 p0 = ext2[s4.x];
        float2 p1 = ext2[s4.y];
        float2 p2 = ext2[s4.z];
        float2 p3 = ext2[s4.w];
        f32x4 va, vb;
        va[0] = p0.x; va[1] = p1.x; va[2] = p2.x; va[3] = p3.x;
        vb[0] = p0.y; vb[1] = p1.y; vb[2] = p2.y; vb[3] = p3.y;
        __builtin_nontemporal_store(va, op0 + qq);
        __builtin_nontemporal_store(vb, op1 + qq);
    }
}

extern "C" void kernel_launch(void* const* d_in, const int* in_sizes, int n_in,
                              void* d_out, int out_size, void* d_ws, size_t ws_size,
                              hipStream_t stream) {
    const float* F      = (const float*)d_in[0];
    const int*   labels = (const int*)d_in[1];
    float*       out    = (float*)d_out;

    const int B = in_sizes[0] / N_GENERA;  // 1024
    char* ws = (char*)d_ws;
    int*   idx   = (int*)(ws + WS_IDX_OFF);
    int*   offs  = (int*)(ws + WS_OFFS_OFF);
    short* sidxN = (short*)(ws + WS_SIDXN_OFF);
    short* sidxO = (short*)(ws + WS_SIDXO_OFF);
    int*   perm  = (int*)(ws + WS_PERM_OFF);
    float* seg   = (float*)(ws + WS_SEG_OFF);

    const size_t ws_need = (size_t)WS_SEG_OFF + (size_t)(B / 4) * SEG_SZ * 16;

    prep_kernel<<<dim3(N_RANKS + 224 + 1), dim3(256), 0, stream>>>(
        labels, idx, offs, sidxN, sidxO, perm);

    if (ws_size >= ws_need && (B % 4) == 0) {
        seg_kernel<<<dim3(B / 4), dim3(512), 0, stream>>>(F, idx, offs, perm, seg);
        gather_kernel<<<dim3(B), dim3(GT), 0, stream>>>(F, seg, sidxN, out);
    } else {
        fused_kernel<<<dim3(B / 2), dim3(512), 0, stream>>>(F, idx, offs, sidxO, out);
    }
}

// Round 4
// 56.853 us; speedup vs baseline: 1.3626x; 1.3626x over previous
//
#include <hip/hip_runtime.h>

#define N_GENERA 4096
#define N_RANKS 6
#define N_GROUPS 256
#define NCH 7                          // 6 ranks + identity channel
#define SEG_SZ (N_RANKS * N_GROUPS)    // 1536
#define EXT_SZ (SEG_SZ + N_GENERA)     // 5632 float2 = 45 KB
#define NF (N_GENERA * NCH)            // 28672 output floats per b
#define NF4 (NF / 4)                   // 7168 float4 per b
#define MAXL 96                        // idxT row cap (Poisson(16) max ~45)

typedef float f32x4 __attribute__((ext_vector_type(4)));

// ws layout:
//   idx  [6][4096]    int   @ 0        (96 KB)   raw CSR
//   offs [6][260]     int   @ 98304
//   sidx [NF]         short @ 104704   (56 KB)   output-float -> ext[] index
//   perm [1536]       int   @ 162048   length-sorted slot -> (r,g)
//   lenT [1536]       int   @ 168192   list length per slot
//   idxT [MAXL][1536] int   @ 174336   (576 KB)  transposed CSR, coalesced rows
#define WS_IDX_OFF   0
#define WS_OFFS_OFF  98304
#define WS_SIDX_OFF  104704
#define WS_PERM_OFF  162048
#define WS_LENT_OFF  168192
#define WS_IDXT_OFF  174336

__device__ __forceinline__ int imin(int a, int b) { return a < b ? a : b; }

// ---------- Kernel 0: prep1 = CSR (0..5) + sidx (6..117) + perm/lenT (118) ----------
__global__ __launch_bounds__(256) void prep1_kernel(
    const int* __restrict__ labels,
    int* __restrict__ idx,      // [R][N_GENERA]
    int* __restrict__ offs,     // [R][260]
    short* __restrict__ sidx,   // [NF]
    int* __restrict__ perm,     // [1536]
    int* __restrict__ lenT)     // [1536]
{
    const int t = threadIdx.x;

    if (blockIdx.x < N_RANKS) {
        const int r = blockIdx.x;
        const int* __restrict__ lab = labels + r * N_GENERA;

        __shared__ int cnt[N_GROUPS];
        __shared__ int scan[N_GROUPS];
        __shared__ int cur[N_GROUPS];

        cnt[t] = 0;
        __syncthreads();
        for (int i = t; i < N_GENERA; i += 256)
            atomicAdd(&cnt[lab[i]], 1);
        __syncthreads();

        int v = cnt[t];
        scan[t] = v;
        __syncthreads();
        #pragma unroll
        for (int s = 1; s < 256; s <<= 1) {
            int add = (t >= s) ? scan[t - s] : 0;
            __syncthreads();
            scan[t] += add;
            __syncthreads();
        }
        int start = scan[t] - v;          // exclusive prefix
        cur[t] = start;
        offs[r * 260 + t] = start;
        if (t == 0) offs[r * 260 + 256] = N_GENERA;
        __syncthreads();
        for (int i = t; i < N_GENERA; i += 256) {
            int p = atomicAdd(&cur[lab[i]], 1);
            idx[r * N_GENERA + p] = i;
        }
    } else if (blockIdx.x < N_RANKS + 112) {
        // sidx: output-float -> ext[]-index map (batch-independent)
        const int f = (blockIdx.x - N_RANKS) * 256 + t;   // < NF
        const int j = f / NCH;
        const int ch = f - j * NCH;
        int v;
        if (ch < N_RANKS)
            v = ch * N_GROUPS + labels[ch * N_GENERA + j];
        else
            v = SEG_SZ + j;               // identity channel -> F slot
        sidx[f] = (short)v;
    } else {
        // perm: count-sort the 1536 (r,g) items by descending count, so a
        // wave's 64 lanes get near-equal CSR list lengths.
        __shared__ int cnt[SEG_SZ];
        __shared__ int hist[64];
        __shared__ int base[64];
        __shared__ int cur[64];
        for (int i = t; i < SEG_SZ; i += 256) cnt[i] = 0;
        if (t < 64) { hist[t] = 0; cur[t] = 0; }
        __syncthreads();
        for (int r = 0; r < N_RANKS; ++r)
            for (int i = t; i < N_GENERA; i += 256)
                atomicAdd(&cnt[r * N_GROUPS + labels[r * N_GENERA + i]], 1);
        __syncthreads();
        for (int p = t; p < SEG_SZ; p += 256)
            atomicAdd(&hist[imin(cnt[p], 63)], 1);
        __syncthreads();
        if (t < 64) {
            int bsum = 0;
            for (int c = t + 1; c < 64; ++c) bsum += hist[c];
            base[t] = bsum;               // descending-count exclusive base
        }
        __syncthreads();
        for (int p = t; p < SEG_SZ; p += 256) {
            int c = imin(cnt[p], 63);
            int slot = base[c] + atomicAdd(&cur[c], 1);
            perm[slot] = p;
            lenT[slot] = cnt[p];
        }
    }
}

// ---------- Kernel 0b: prep2 = transpose CSR into idxT (coalesced rows) ----------
__global__ __launch_bounds__(256) void prep2_kernel(
    const int* __restrict__ idx,
    const int* __restrict__ offs,
    const int* __restrict__ perm,
    int* __restrict__ idxT)           // [MAXL][1536]
{
    const int s = blockIdx.x * 256 + threadIdx.x;   // slot < 1536
    const int p = perm[s];
    const int r = p >> 8;
    const int g = p & 255;
    const int beg = offs[r * 260 + g];
    const int e   = offs[r * 260 + g + 1];
    const int lm = imin(e - beg, MAXL);
    const int* __restrict__ ip = idx + r * N_GENERA + beg;
    for (int k = 0; k < lm; ++k)
        idxT[k * SEG_SZ + s] = ip[k];
}

// ---------- Kernel 1: fused CSR-seg + gather, TWO batch rows per block ----------
// LDS ext2[] = { seg[1536] | Frow[4096] } of float2 = {val_b0, val_b1} (45 KB).
// Phase A: balanced slots via perm; idxT rows are wave-coalesced 256B reads
//          (kills the per-lane-cache-line L2 storm); Fl2 random ds_read_b64
//          serves both b's.
// Phase B: coalesced short4 sidx read, 4 ds_read_b64 gathers, 2 contiguous
//          nontemporal float4 stores. Two barriers total.
__global__ __launch_bounds__(512) void fused_kernel(
    const float* __restrict__ F,
    const int* __restrict__ idx,
    const int* __restrict__ offs,
    const int* __restrict__ perm,
    const int* __restrict__ lenT,
    const int* __restrict__ idxT,
    const short* __restrict__ sidx,
    float* __restrict__ out)
{
    __shared__ float2 ext2[EXT_SZ];
    const int b0 = blockIdx.x * 2;
    const int t = threadIdx.x;

    // stage 2 F rows pair-interleaved into ext2[SEG_SZ..)
    const f32x4* Fv0 = reinterpret_cast<const f32x4*>(F + (size_t)b0 * N_GENERA);
    const f32x4* Fv1 = reinterpret_cast<const f32x4*>(F + (size_t)(b0 + 1) * N_GENERA);
    f32x4* Flv = reinterpret_cast<f32x4*>(ext2 + SEG_SZ);
    #pragma unroll
    for (int k = 0; k < 2; ++k) {
        const f32x4 a = __builtin_nontemporal_load(Fv0 + t + k * 512);
        const f32x4 c = __builtin_nontemporal_load(Fv1 + t + k * 512);
        f32x4 lo, hi;
        lo[0] = a[0]; lo[1] = c[0]; lo[2] = a[1]; lo[3] = c[1];
        hi[0] = a[2]; hi[1] = c[2]; hi[2] = a[3]; hi[3] = c[3];
        Flv[2 * (t + k * 512)]     = lo;
        Flv[2 * (t + k * 512) + 1] = hi;
    }
    __syncthreads();

    // Phase A: segment sums for both b's, 3 sorted slots per thread
    const float2* __restrict__ Fl2 = ext2 + SEG_SZ;
    #pragma unroll
    for (int w = 0; w < 3; ++w) {
        const int s = t + w * 512;
        const int p = perm[s];
        const int len = lenT[s];
        const int lm = imin(len, MAXL);
        const int* __restrict__ col = idxT + s;   // row stride SEG_SZ
        float sa = 0.f, sb = 0.f;
        int k = 0;
        for (; k + 4 <= lm; k += 4) {
            const int i0 = col[(k    ) * SEG_SZ];
            const int i1 = col[(k + 1) * SEG_SZ];
            const int i2 = col[(k + 2) * SEG_SZ];
            const int i3 = col[(k + 3) * SEG_SZ];
            float2 v0 = Fl2[i0], v1 = Fl2[i1], v2 = Fl2[i2], v3 = Fl2[i3];
            sa += (v0.x + v1.x) + (v2.x + v3.x);
            sb += (v0.y + v1.y) + (v2.y + v3.y);
        }
        for (; k < lm; ++k) {
            float2 v = Fl2[col[k * SEG_SZ]];
            sa += v.x; sb += v.y;
        }
        if (len > MAXL) {                 // safety net; never taken in practice
            const int r = p >> 8, g = p & 255;
            const int beg = offs[r * 260 + g];
            const int* __restrict__ ip = idx + r * N_GENERA + beg;
            for (int k2 = MAXL; k2 < len; ++k2) {
                float2 v = Fl2[ip[k2]];
                sa += v.x; sb += v.y;
            }
        }
        float2 sp; sp.x = sa; sp.y = sb;
        ext2[p] = sp;   // seg region; disjoint from F region being read
    }
    __syncthreads();

    // Phase B: 14 output float4 per b per thread, lanes contiguous per store
    f32x4* __restrict__ op0 = reinterpret_cast<f32x4*>(out) + (size_t)b0 * NF4;
    f32x4* __restrict__ op1 = op0 + NF4;
    #pragma unroll
    for (int kk = 0; kk < 14; ++kk) {
        const int q = kk * 512 + t;
        short4 s4 = *reinterpret_cast<const short4*>(sidx + q * 4);
        float2 p0 = ext2[s4.x];
        float2 p1 = ext2[s4.y];
        float2 p2 = ext2[s4.z];
        float2 p3 = ext2[s4.w];
        f32x4 va, vb;
        va[0] = p0.x; va[1] = p1.x; va[2] = p2.x; va[3] = p3.x;
        vb[0] = p0.y; vb[1] = p1.y; vb[2] = p2.y; vb[3] = p3.y;
        __builtin_nontemporal_store(va, op0 + q);
        __builtin_nontemporal_store(vb, op1 + q);
    }
}

extern "C" void kernel_launch(void* const* d_in, const int* in_sizes, int n_in,
                              void* d_out, int out_size, void* d_ws, size_t ws_size,
                              hipStream_t stream) {
    const float* F      = (const float*)d_in[0];
    const int*   labels = (const int*)d_in[1];
    float*       out    = (float*)d_out;

    const int B = in_sizes[0] / N_GENERA;  // 1024
    char* ws = (char*)d_ws;
    int*   idx  = (int*)(ws + WS_IDX_OFF);
    int*   offs = (int*)(ws + WS_OFFS_OFF);
    short* sidx = (short*)(ws + WS_SIDX_OFF);
    int*   perm = (int*)(ws + WS_PERM_OFF);
    int*   lenT = (int*)(ws + WS_LENT_OFF);
    int*   idxT = (int*)(ws + WS_IDXT_OFF);

    prep1_kernel<<<dim3(N_RANKS + 112 + 1), dim3(256), 0, stream>>>(
        labels, idx, offs, sidx, perm, lenT);
    prep2_kernel<<<dim3(SEG_SZ / 256), dim3(256), 0, stream>>>(idx, offs, perm, idxT);
    fused_kernel<<<dim3(B / 2), dim3(512), 0, stream>>>(
        F, idx, offs, perm, lenT, idxT, sidx, out);
}